// Round 1
// 1239.995 us; speedup vs baseline: 1.1239x; 1.1239x over previous
//
#include <hip/hip_runtime.h>
#include <hip/hip_fp16.h>

#define RES 512
#define CHAN 16
#define HW (RES * RES)          // 262144 locations per plane
#define PLANE_F (CHAN * HW)     // fp32 floats per plane, original layout

// ---------------------------------------------------------------------------
// Pass 1: transpose + downconvert (3, 16, 512, 512) fp32 -> (3, 512, 512, 16)
// fp16, so the 16 channels at one (h,w) are a contiguous 32B block.
//
// Block = 256 threads = 128 locations x 2 channel-halves.
//   half = tid & 1  -> channels [half*8, half*8+8)
//   w    = strip*128 + (tid >> 1)
// Reads:  per load instruction, two 128B contiguous segments (one per half).
// Writes: one uint4 (16B) per lane, lane-contiguous -> perfectly coalesced.
// Volume: 48 MB read + 24 MB write  (was 48+48 with 16B-stride-64B stores).
// ---------------------------------------------------------------------------
__global__ __launch_bounds__(256) void triplane_transpose_f16(
    const float* __restrict__ src, uint4* __restrict__ dst) {
  int b    = blockIdx.x;
  int p    = b >> 11;            // 2048 blocks per plane (512 h * 4 strips)
  int rem  = b & 2047;
  int h    = rem >> 2;
  int strip= rem & 3;
  int half = threadIdx.x & 1;
  int w    = (strip << 7) + (threadIdx.x >> 1);

  const float* s = src + (size_t)(p * CHAN + half * 8) * HW + h * RES + w;

  uint u[4];
#pragma unroll
  for (int k = 0; k < 4; ++k) {
    float f0 = s[(size_t)(2 * k + 0) * HW];
    float f1 = s[(size_t)(2 * k + 1) * HW];
    uint lo = (uint)__half_as_ushort(__float2half_rn(f0));
    uint hi = (uint)__half_as_ushort(__float2half_rn(f1));
    u[k] = lo | (hi << 16);
  }
  // 32B per location; this thread owns 16B of it (channels half*8..half*8+7)
  dst[((size_t)p * HW + h * RES + w) * 2 + half] = make_uint4(u[0], u[1], u[2], u[3]);
}

// ---------------------------------------------------------------------------
// Helper: 4 packed fp16 -> float4
// ---------------------------------------------------------------------------
__device__ __forceinline__ float4 h4_to_f4(uint2 u) {
  __half2 h0 = *reinterpret_cast<const __half2*>(&u.x);
  __half2 h1 = *reinterpret_cast<const __half2*>(&u.y);
  float2 f0 = __half22float2(h0);
  float2 f1 = __half22float2(h1);
  return make_float4(f0.x, f0.y, f1.x, f1.y);
}

// ---------------------------------------------------------------------------
// Pass 2: one thread per (point, channel-quad).  gid = p*12 + q.
//   q/4 == 0 -> f_xy : plane 0, coords (x, y)
//   q/4 == 1 -> f_yz : plane 2, coords (y, z/0.05)
//   q/4 == 2 -> f_zx : plane 1, coords (z/0.05, x)
// TRANSPOSED path: 4 corner uint2 (half4) gathers from the fp16 map +
// 1 perfectly-coalesced float4 store.  Weights/coords in fp32 (unchanged).
// ---------------------------------------------------------------------------
template <bool TRANSPOSED>
__global__ __launch_bounds__(256) void triplane_gather(
    const float* __restrict__ xyz, const void* __restrict__ fm,
    float* __restrict__ out, int n12) {
  int gid = blockIdx.x * 256 + threadIdx.x;
  if (gid >= n12) return;

  int p  = gid / 12;                  // umulhi under the hood
  int q  = gid - p * 12;
  int s  = q >> 2;                    // segment 0,1,2
  int cq = q & 3;                     // channel quad

  float x = xyz[p * 3 + 0];
  float y = xyz[p * 3 + 1];
  float z = xyz[p * 3 + 2];
  float zs = z / 0.05f;               // match reference's division semantics

  // branchless plane/coord select
  float a  = (s == 0) ? x : ((s == 1) ? y : zs);
  float b  = (s == 0) ? y : ((s == 1) ? zs : x);
  int   pl = (s == 0) ? 0 : ((s == 1) ? 2 : 1);

  float u = (a + 1.0f) * 255.5f;      // (D0-1)*0.5, D0 = 512
  float v = (b + 1.0f) * 255.5f;

  float x0 = floorf(u), y0 = floorf(v);
  float x1 = x0 + 1.0f, y1 = y0 + 1.0f;

  float wa = (x1 - u) * (y1 - v);
  float wb = (u - x0) * (y1 - v);
  float wc = (x1 - u) * (v - y0);
  float wd = (u - x0) * (v - y0);

  int x0i = (int)fminf(fmaxf(x0, 0.0f), 510.0f);
  int x1i = (int)fminf(fmaxf(x1, 1.0f), 511.0f);
  int y0i = (int)fminf(fmaxf(y0, 0.0f), 510.0f);
  int y1i = (int)fminf(fmaxf(y1, 1.0f), 511.0f);

  float4 r;
  if (TRANSPOSED) {
    // fp16 map: plane = HW locations * 32B = HW*4 uint2
    const uint2* base = (const uint2*)fm + (size_t)pl * (HW * 4);
    uint2 A = base[(size_t)(x0i * RES + y0i) * 4 + cq];
    uint2 B = base[(size_t)(x1i * RES + y0i) * 4 + cq];
    uint2 C = base[(size_t)(x0i * RES + y1i) * 4 + cq];
    uint2 D = base[(size_t)(x1i * RES + y1i) * 4 + cq];
    float4 fA = h4_to_f4(A);
    float4 fB = h4_to_f4(B);
    float4 fC = h4_to_f4(C);
    float4 fD = h4_to_f4(D);
    r.x = wa * fA.x + wb * fB.x + wc * fC.x + wd * fD.x;
    r.y = wa * fA.y + wb * fB.y + wc * fC.y + wd * fD.y;
    r.z = wa * fA.z + wb * fB.z + wc * fC.z + wd * fD.z;
    r.w = wa * fA.w + wb * fB.w + wc * fC.w + wd * fD.w;
  } else {
    // fallback: gather fp32 from original (C,H,W) layout (channel stride 1MB)
    const float* fbase = (const float*)fm + (size_t)pl * PLANE_F + (size_t)(cq * 4) * HW;
    float acc[4];
#pragma unroll
    for (int j = 0; j < 4; ++j) {
      const float* ch = fbase + (size_t)j * HW;
      float A = ch[x0i * RES + y0i];
      float B = ch[x1i * RES + y0i];
      float C = ch[x0i * RES + y1i];
      float D = ch[x1i * RES + y1i];
      acc[j] = wa * A + wb * B + wc * C + wd * D;
    }
    r = make_float4(acc[0], acc[1], acc[2], acc[3]);
  }

  ((float4*)out)[gid] = r;
}

extern "C" void kernel_launch(void* const* d_in, const int* in_sizes, int n_in,
                              void* d_out, int out_size, void* d_ws, size_t ws_size,
                              hipStream_t stream) {
  const float* xyz = (const float*)d_in[0];
  const float* fm  = (const float*)d_in[1];
  float* out = (float*)d_out;

  int N   = in_sizes[0] / 3;
  int n12 = N * 12;
  int grid = (n12 + 255) / 256;

  size_t need = (size_t)3 * HW * CHAN * sizeof(unsigned short);  // 24 MB fp16
  if (ws_size >= need) {
    triplane_transpose_f16<<<3 * 2048, 256, 0, stream>>>(fm, (uint4*)d_ws);
    triplane_gather<true><<<grid, 256, 0, stream>>>(xyz, d_ws, out, n12);
  } else {
    triplane_gather<false><<<grid, 256, 0, stream>>>(xyz, fm, out, n12);
  }
}